// Round 7
// baseline (361.715 us; speedup 1.0000x reference)
//
#include <hip/hip_runtime.h>

typedef __bf16 bf16;
typedef bf16 bf16x2 __attribute__((ext_vector_type(2)));
typedef bf16 bf16x4 __attribute__((ext_vector_type(4)));
typedef bf16 bf16x8 __attribute__((ext_vector_type(8)));
typedef float f32x4 __attribute__((ext_vector_type(4)));
typedef float f32x16 __attribute__((ext_vector_type(16)));
typedef unsigned int u32;
typedef u32 u32x4 __attribute__((ext_vector_type(4)));
typedef float4 f4;

constexpr int BHN = 64;   // B*H
constexpr int LN  = 4096;
constexpr int DN  = 64;
constexpr int MN  = 266;  // real feature rows
constexpr int MP  = 320;  // padded to 5*64 (workspace only written for m<MN)
constexpr int STR = 72;   // LDS row stride in bf16 (144B, 16B-aligned)
constexpr int KVS = 328;  // kv LDS row stride in bf16 (656B)
constexpr int LSP = 16;   // l-chunks in kernel A's grid
#define EPSF 1e-3f

#define MFMA32(A, B, C) __builtin_amdgcn_mfma_f32_32x32x16_bf16(A, B, C, 0, 0, 0)

__device__ __forceinline__ u32 cvt_pk_bf16(float lo, float hi) {
  u32 r;
  asm("v_cvt_pk_bf16_f32 %0, %1, %2" : "=v"(r) : "v"(lo), "v"(hi));
  return r;
}

// ---------------------------------------------------------------------------
// Kernel A v4: r6 structure + (a) grid 16 l-chunks for 3-block/CU residency,
// (b) constant-trip wave-role-split staging so all stage loads issue in one
// burst (full unroll), (c) launch_bounds(320,4) pinning VGPR <= 128.
//   kvT[bh][d][m] += V^T·kp,  ksum[bh][m] += sum_l kp,  kp = relu(K·projT)+eps
// grid (16 l-chunks, 64 bh) x 320 threads (wave w owns m in [64w, 64w+64))
// ---------------------------------------------------------------------------
__global__ __launch_bounds__(320, 4) void perf_kv_mfma32(
    const float* __restrict__ kg, const float* __restrict__ vg,
    const float* __restrict__ proj, float* __restrict__ kv_ws,
    float* __restrict__ ksum_ws)
{
  __shared__ __align__(16) bf16 k_lds[64 * STR];   // [l][d]  9216 B
  __shared__ __align__(16) bf16 vt_lds[64 * STR];  // [d][l]  9216 B

  const int t    = threadIdx.x;
  const int wid  = t >> 6;      // 0..4
  const int lane = t & 63;
  const int ln31 = lane & 31;
  const int hi   = lane >> 5;
  const int lsp  = blockIdx.x;  // 0..15
  const int bh   = blockIdx.y;  // 0..63
  const int mw   = wid * 64;

  // proj B-fragments, register-resident: col m = mw+mt*32+ln31, k(d)=ks*16+hi*8+e
  bf16x8 pb[2][4];
#pragma unroll
  for (int mt = 0; mt < 2; ++mt) {
    const int m = mw + mt * 32 + ln31;
#pragma unroll
    for (int ks = 0; ks < 4; ++ks) {
      bf16x8 w = {};
      if (m < MN) {
        const float* p = proj + m * 64 + ks * 16 + hi * 8;
        f4 a = *(const f4*)p;
        f4 b = *(const f4*)(p + 4);
        w = (bf16x8){(bf16)a.x, (bf16)a.y, (bf16)a.z, (bf16)a.w,
                     (bf16)b.x, (bf16)b.y, (bf16)b.z, (bf16)b.w};
      }
      pb[mt][ks] = w;
    }
  }

  f32x16 acc[2][2];  // [dt][mt]: kvT rows d = dt*32+(r&3)+8(r>>2)+4hi, col m
  acc[0][0] = (f32x16){}; acc[0][1] = (f32x16){};
  acc[1][0] = (f32x16){}; acc[1][1] = (f32x16){};
  float ksum_acc[2] = {0.f, 0.f};

  const float* kbase = kg + (size_t)bh * LN * 64;
  const float* vbase = vg + (size_t)bh * LN * 64;

  for (int ls = 0; ls < LN / (LSP * 64); ++ls) {  // 4 tiles of 64 l
    const int l0 = lsp * (LN / LSP) + ls * 64;
    __syncthreads();  // previous tile fully consumed
    // stage K [64 l][64 d]: waves 0-3, exactly 4 f4/thread (compile-time trip)
    if (t < 256) {
#pragma unroll
      for (int i = 0; i < 4; ++i) {
        int idx = t + i * 256;
        int row = idx >> 4, d4 = idx & 15;
        f4 val = *((const f4*)(kbase + (size_t)(l0 + row) * 64) + d4);
        bf16x4 w = {(bf16)val.x, (bf16)val.y, (bf16)val.z, (bf16)val.w};
        *(bf16x4*)&k_lds[row * STR + d4 * 4] = w;
      }
    }
    // stage V^T [64 d][64 l]: waves 3-4, exactly 4 units (8 f4)/thread
    if (t >= 192) {
#pragma unroll
      for (int j = 0; j < 4; ++j) {
        int u = (t - 192) + j * 128;   // 0..511
        int lb2 = u >> 4, d4 = u & 15;
        const float* vp = vbase + (size_t)(l0 + lb2 * 2) * 64 + d4 * 4;
        f4 a = *(const f4*)vp;
        f4 b = *(const f4*)(vp + 64);
        bf16x2 w0 = {(bf16)a.x, (bf16)b.x};
        bf16x2 w1 = {(bf16)a.y, (bf16)b.y};
        bf16x2 w2 = {(bf16)a.z, (bf16)b.z};
        bf16x2 w3 = {(bf16)a.w, (bf16)b.w};
        *(bf16x2*)&vt_lds[(d4 * 4 + 0) * STR + lb2 * 2] = w0;
        *(bf16x2*)&vt_lds[(d4 * 4 + 1) * STR + lb2 * 2] = w1;
        *(bf16x2*)&vt_lds[(d4 * 4 + 2) * STR + lb2 * 2] = w2;
        *(bf16x2*)&vt_lds[(d4 * 4 + 3) * STR + lb2 * 2] = w3;
      }
    }
    __syncthreads();  // tile ready

#pragma unroll
    for (int lt = 0; lt < 2; ++lt) {
      // K A-fragments: row l = l0+lt*32+ln31, k(d) = ks*16+hi*8+e
      bf16x8 ka[4];
#pragma unroll
      for (int ks = 0; ks < 4; ++ks)
        ka[ks] = *(const bf16x8*)&k_lds[(lt * 32 + ln31) * STR + ks * 16 + hi * 8];
      // V^T A-fragments: row d = dt*32+ln31, k(l) = lt*32+kk*16+hi*8+e
      bf16x8 va[2][2];
#pragma unroll
      for (int dt = 0; dt < 2; ++dt)
#pragma unroll
        for (int kk = 0; kk < 2; ++kk)
          va[dt][kk] = *(const bf16x8*)&vt_lds[(dt * 32 + ln31) * STR + lt * 32 + kk * 16 + hi * 8];

#pragma unroll
      for (int mt = 0; mt < 2; ++mt) {
        // feature: C1[l][m] = K·projT (lane = m-col, regs = l-rows)
        f32x16 f = (f32x16){};
#pragma unroll
        for (int ks = 0; ks < 4; ++ks) f = MFMA32(ka[ks], pb[mt][ks], f);
#pragma unroll
        for (int i = 0; i < 16; ++i) f[i] = fmaxf(f[i], 0.f) + EPSF;
        ksum_acc[mt] += f[0] + f[1] + f[2] + f[3] + f[4] + f[5] + f[6] + f[7]
                      + f[8] + f[9] + f[10] + f[11] + f[12] + f[13] + f[14] + f[15];
        // T12: pack to bf16 words, permlane-swap into B-operand (col=m, k=l)
        u32 w0 = cvt_pk_bf16(f[0], f[1]);
        u32 w1 = cvt_pk_bf16(f[2], f[3]);
        u32 w2 = cvt_pk_bf16(f[4], f[5]);
        u32 w3 = cvt_pk_bf16(f[6], f[7]);
        u32 w4 = cvt_pk_bf16(f[8], f[9]);
        u32 w5 = cvt_pk_bf16(f[10], f[11]);
        u32 w6 = cvt_pk_bf16(f[12], f[13]);
        u32 w7 = cvt_pk_bf16(f[14], f[15]);
        asm("v_permlane32_swap_b32 %0, %1" : "+v"(w0), "+v"(w2));
        asm("v_permlane32_swap_b32 %0, %1" : "+v"(w1), "+v"(w3));
        asm("v_permlane32_swap_b32 %0, %1" : "+v"(w4), "+v"(w6));
        asm("v_permlane32_swap_b32 %0, %1" : "+v"(w5), "+v"(w7));
        u32x4 a0 = {w0, w1, w2, w3};
        u32x4 a1 = {w4, w5, w6, w7};
        bf16x8 kb0 = __builtin_bit_cast(bf16x8, a0);  // k = l rel 0..15
        bf16x8 kb1 = __builtin_bit_cast(bf16x8, a1);  // k = l rel 16..31
        acc[0][mt] = MFMA32(va[0][0], kb0, acc[0][mt]);
        acc[1][mt] = MFMA32(va[1][0], kb0, acc[1][mt]);
        acc[0][mt] = MFMA32(va[0][1], kb1, acc[0][mt]);
        acc[1][mt] = MFMA32(va[1][1], kb1, acc[1][mt]);
      }
    }
  }

  // epilogue: f32 atomics into workspace (guarded: padded m stays exactly 0)
#pragma unroll
  for (int mt = 0; mt < 2; ++mt) {
    const int m = mw + mt * 32 + ln31;
    if (m < MN) {
#pragma unroll
      for (int dt = 0; dt < 2; ++dt) {
#pragma unroll
        for (int r = 0; r < 16; ++r) {
          const int d = dt * 32 + (r & 3) + 8 * (r >> 2) + 4 * hi;
          atomicAdd(&kv_ws[((size_t)bh * 64 + d) * MP + m], acc[dt][mt][r]);
        }
      }
    }
    float r = ksum_acc[mt];
    r += __shfl_xor(r, 32);
    if (hi == 0 && m < MN) atomicAdd(&ksum_ws[bh * MP + m], r);
  }
}

// ---------------------------------------------------------------------------
// Kernel C: one-shot f32 -> bf16 conversion of kv workspace and proj
// ---------------------------------------------------------------------------
__global__ __launch_bounds__(256) void perf_cvt(
    const float* __restrict__ kv_ws, const float* __restrict__ proj,
    bf16* __restrict__ kv_b, bf16* __restrict__ pj_b)
{
  const int KV4 = BHN * DN * MP / 4;  // 327680
  const int PJ4 = MP * DN / 4;        // 5120
  int idx = blockIdx.x * 256 + threadIdx.x;
  if (idx < KV4) {
    f4 v = reinterpret_cast<const f4*>(kv_ws)[idx];
    bf16x4 w = {(bf16)v.x, (bf16)v.y, (bf16)v.z, (bf16)v.w};
    *(bf16x4*)&kv_b[idx * 4] = w;
  } else if (idx < KV4 + PJ4) {
    int p = idx - KV4;
    int m = p >> 4;
    f4 v = {0.f, 0.f, 0.f, 0.f};
    if (m < MN) v = reinterpret_cast<const f4*>(proj)[p];
    bf16x4 w = {(bf16)v.x, (bf16)v.y, (bf16)v.z, (bf16)v.w};
    *(bf16x4*)&pj_b[p * 4] = w;
  }
}

// ---------------------------------------------------------------------------
// Kernel B (unchanged from round 4, verified): 32x32 MFMA, whole-M LDS-resident
// ---------------------------------------------------------------------------
__global__ __launch_bounds__(512, 2) void perf_out_mfma32(
    const float* __restrict__ qg, const bf16* __restrict__ pjb,
    const bf16* __restrict__ kvb, const float* __restrict__ ksum_ws,
    float* __restrict__ outg)
{
  __shared__ __align__(16) bf16 pj_lds[MP * STR];   // [m][d]   46080 B
  __shared__ __align__(16) bf16 kv_lds[DN * KVS];   // [d][m]   41984 B
  __shared__ __align__(16) float ksum_lds[MP];
  __shared__ float dp_lds[8 * 64];

  const int t    = threadIdx.x;
  const int wid  = t >> 6;
  const int lane = t & 63;
  const int ln31 = lane & 31;
  const int hi   = lane >> 5;
  const int bh   = blockIdx.y;
  const int lbase = blockIdx.x * 1024;

  for (int idx = t; idx < MP * 8; idx += 512) {
    int r = idx >> 3, c8 = idx & 7;
    *(bf16x8*)&pj_lds[r * STR + c8 * 8] = *(const bf16x8*)&pjb[r * 64 + c8 * 8];
  }
  for (int idx = t; idx < DN * 40; idx += 512) {
    int r = idx / 40, cc = idx % 40;
    *(bf16x8*)&kv_lds[r * KVS + cc * 8] =
        *(const bf16x8*)&kvb[((size_t)bh * DN + r) * MP + cc * 8];
  }
  if (t < MP) ksum_lds[t] = ksum_ws[bh * MP + t];
  __syncthreads();  // the only block barrier

  for (int rnd = 0; rnd < 2; ++rnd) {
    const int lw = lbase + rnd * 512 + wid * 64;

    bf16x8 qb[2][4];
#pragma unroll
    for (int lt = 0; lt < 2; ++lt)
#pragma unroll
      for (int ks = 0; ks < 4; ++ks) {
        const float* qp_ = qg + ((size_t)bh * LN + lw + lt * 32 + ln31) * 64 + ks * 16 + hi * 8;
        f4 a = *(const f4*)qp_;
        f4 b = *(const f4*)(qp_ + 4);
        qb[lt][ks] = (bf16x8){(bf16)a.x, (bf16)a.y, (bf16)a.z, (bf16)a.w,
                              (bf16)b.x, (bf16)b.y, (bf16)b.z, (bf16)b.w};
      }

    f32x16 oc[2][2];
    oc[0][0] = (f32x16){}; oc[0][1] = (f32x16){};
    oc[1][0] = (f32x16){}; oc[1][1] = (f32x16){};
    float dp[2] = {0.f, 0.f};

    for (int mc = 0; mc < 5; ++mc) {
      f32x16 c2[2][2];
      c2[0][0] = (f32x16){}; c2[0][1] = (f32x16){};
      c2[1][0] = (f32x16){}; c2[1][1] = (f32x16){};
#pragma unroll
      for (int ks = 0; ks < 4; ++ks) {
        bf16x8 pa0 = *(const bf16x8*)&pj_lds[(mc * 64 + ln31) * STR + ks * 16 + hi * 8];
        bf16x8 pa1 = *(const bf16x8*)&pj_lds[(mc * 64 + 32 + ln31) * STR + ks * 16 + hi * 8];
        c2[0][0] = MFMA32(pa0, qb[0][ks], c2[0][0]);
        c2[1][0] = MFMA32(pa0, qb[1][ks], c2[1][0]);
        c2[0][1] = MFMA32(pa1, qb[0][ks], c2[0][1]);
        c2[1][1] = MFMA32(pa1, qb[1][ks], c2[1][1]);
      }
#pragma unroll
      for (int mt = 0; mt < 2; ++mt) {
        const int mb = mc * 64 + mt * 32 + 4 * hi;
        f32x4 kq0 = *(const f32x4*)&ksum_lds[mb + 0];
        f32x4 kq1 = *(const f32x4*)&ksum_lds[mb + 8];
        f32x4 kq2 = *(const f32x4*)&ksum_lds[mb + 16];
        f32x4 kq3 = *(const f32x4*)&ksum_lds[mb + 24];
        bf16x8 A[2][2];
#pragma unroll
        for (int lt = 0; lt < 2; ++lt) {
          f32x16 f = c2[lt][mt];
#pragma unroll
          for (int i = 0; i < 16; ++i) f[i] = fmaxf(f[i], 0.f) + EPSF;
          dp[lt] += f[0] * kq0[0] + f[1] * kq0[1] + f[2] * kq0[2] + f[3] * kq0[3]
                  + f[4] * kq1[0] + f[5] * kq1[1] + f[6] * kq1[2] + f[7] * kq1[3]
                  + f[8] * kq2[0] + f[9] * kq2[1] + f[10] * kq2[2] + f[11] * kq2[3]
                  + f[12] * kq3[0] + f[13] * kq3[1] + f[14] * kq3[2] + f[15] * kq3[3];
          u32 w0 = cvt_pk_bf16(f[0], f[1]);
          u32 w1 = cvt_pk_bf16(f[2], f[3]);
          u32 w2 = cvt_pk_bf16(f[4], f[5]);
          u32 w3 = cvt_pk_bf16(f[6], f[7]);
          u32 w4 = cvt_pk_bf16(f[8], f[9]);
          u32 w5 = cvt_pk_bf16(f[10], f[11]);
          u32 w6 = cvt_pk_bf16(f[12], f[13]);
          u32 w7 = cvt_pk_bf16(f[14], f[15]);
          asm("v_permlane32_swap_b32 %0, %1" : "+v"(w0), "+v"(w2));
          asm("v_permlane32_swap_b32 %0, %1" : "+v"(w1), "+v"(w3));
          asm("v_permlane32_swap_b32 %0, %1" : "+v"(w4), "+v"(w6));
          asm("v_permlane32_swap_b32 %0, %1" : "+v"(w5), "+v"(w7));
          u32x4 a0 = {w0, w1, w2, w3};
          u32x4 a1 = {w4, w5, w6, w7};
          A[lt][0] = __builtin_bit_cast(bf16x8, a0);
          A[lt][1] = __builtin_bit_cast(bf16x8, a1);
        }
#pragma unroll
        for (int kk = 0; kk < 2; ++kk) {
          const int mo = mc * 64 + (mt * 2 + kk) * 16 + hi * 8;
          bf16x8 kb0 = *(const bf16x8*)&kv_lds[ln31 * KVS + mo];
          bf16x8 kb1 = *(const bf16x8*)&kv_lds[(32 + ln31) * KVS + mo];
          oc[0][0] = MFMA32(A[0][kk], kb0, oc[0][0]);
          oc[1][0] = MFMA32(A[1][kk], kb0, oc[1][0]);
          oc[0][1] = MFMA32(A[0][kk], kb1, oc[0][1]);
          oc[1][1] = MFMA32(A[1][kk], kb1, oc[1][1]);
        }
      }
    }

#pragma unroll
    for (int lt = 0; lt < 2; ++lt) {
      float r = dp[lt];
      r += __shfl_xor(r, 32);
      dp_lds[wid * 64 + lt * 32 + ln31] = r;
    }
#pragma unroll
    for (int lt = 0; lt < 2; ++lt) {
#pragma unroll
      for (int rg = 0; rg < 4; ++rg) {
        f32x4 dv = *(const f32x4*)&dp_lds[wid * 64 + lt * 32 + 8 * rg + 4 * hi];
        f32x4 di = {1.f / dv[0], 1.f / dv[1], 1.f / dv[2], 1.f / dv[3]};
#pragma unroll
        for (int dt = 0; dt < 2; ++dt) {
#pragma unroll
          for (int j = 0; j < 4; ++j) {
            int l = lw + lt * 32 + 8 * rg + 4 * hi + j;
            outg[((size_t)bh * LN + l) * DN + dt * 32 + ln31] = oc[lt][dt][4 * rg + j] * di[j];
          }
        }
      }
    }
  }
}

// ---------------------------------------------------------------------------
extern "C" void kernel_launch(void* const* d_in, const int* in_sizes, int n_in,
                              void* d_out, int out_size, void* d_ws, size_t ws_size,
                              hipStream_t stream)
{
  const float* q    = (const float*)d_in[0];
  const float* k    = (const float*)d_in[1];
  const float* v    = (const float*)d_in[2];
  const float* proj = (const float*)d_in[3];
  float* out     = (float*)d_out;

  float* kv_ws   = (float*)d_ws;                        // [64][64][320] f32
  float* ksum_ws = kv_ws + (size_t)BHN * DN * MP;       // [64][320] f32
  bf16*  kv_b    = (bf16*)(ksum_ws + (size_t)BHN * MP); // [64][64][320] bf16
  bf16*  pj_b    = kv_b + (size_t)BHN * DN * MP;        // [320][64] bf16

  size_t zero_bytes = ((size_t)BHN * DN * MP + (size_t)BHN * MP) * sizeof(float);
  hipMemsetAsync(d_ws, 0, zero_bytes, stream);

  perf_kv_mfma32<<<dim3(LSP, BHN), 320, 0, stream>>>(k, v, proj, kv_ws, ksum_ws);

  const int CVT_ITEMS = BHN * DN * MP / 4 + MP * DN / 4;
  perf_cvt<<<(CVT_ITEMS + 255) / 256, 256, 0, stream>>>(kv_ws, proj, kv_b, pj_b);

  perf_out_mfma32<<<dim3(LN / 1024, BHN), 512, 0, stream>>>(q, pj_b, kv_b, ksum_ws, out);
}

// Round 8
// 135.878 us; speedup vs baseline: 2.6621x; 2.6621x over previous
//
#include <hip/hip_runtime.h>

typedef __bf16 bf16;
typedef bf16 bf16x2 __attribute__((ext_vector_type(2)));
typedef bf16 bf16x4 __attribute__((ext_vector_type(4)));
typedef bf16 bf16x8 __attribute__((ext_vector_type(8)));
typedef float f32x4 __attribute__((ext_vector_type(4)));
typedef float f32x16 __attribute__((ext_vector_type(16)));
typedef unsigned int u32;
typedef u32 u32x4 __attribute__((ext_vector_type(4)));
typedef float4 f4;

constexpr int BHN = 64;   // B*H
constexpr int LN  = 4096;
constexpr int DN  = 64;
constexpr int MN  = 266;  // real feature rows
constexpr int MP  = 320;  // padded (pad entries stored as exact 0)
constexpr int STR = 72;   // K/pj LDS stride in bf16 (144B)
constexpr int VTS = 136;  // V^T LDS stride in bf16 (272B)
constexpr int KVS = 328;  // B's kv LDS stride in bf16
constexpr int TL  = 128;  // kernel A l-tile
constexpr int NT  = LN / TL;  // 32
#define EPSF 1e-3f

#define MFMA32(A, B, C) __builtin_amdgcn_mfma_f32_32x32x16_bf16(A, B, C, 0, 0, 0)

__device__ __forceinline__ u32 cvt_pk_bf16(float lo, float hi) {
  u32 r;
  asm("v_cvt_pk_bf16_f32 %0, %1, %2" : "=v"(r) : "v"(lo), "v"(hi));
  return r;
}

// transform feature regs (rows=l, col=m lane) -> kv-MFMA B-operand (k=l, col=m)
#define T12_TRANSFORM(f, kb0, kb1)                                   \
  {                                                                  \
    u32 w0 = cvt_pk_bf16(f[0], f[1]);                                \
    u32 w1 = cvt_pk_bf16(f[2], f[3]);                                \
    u32 w2 = cvt_pk_bf16(f[4], f[5]);                                \
    u32 w3 = cvt_pk_bf16(f[6], f[7]);                                \
    u32 w4 = cvt_pk_bf16(f[8], f[9]);                                \
    u32 w5 = cvt_pk_bf16(f[10], f[11]);                              \
    u32 w6 = cvt_pk_bf16(f[12], f[13]);                              \
    u32 w7 = cvt_pk_bf16(f[14], f[15]);                              \
    asm("v_permlane32_swap_b32 %0, %1" : "+v"(w0), "+v"(w2));        \
    asm("v_permlane32_swap_b32 %0, %1" : "+v"(w1), "+v"(w3));        \
    asm("v_permlane32_swap_b32 %0, %1" : "+v"(w4), "+v"(w6));        \
    asm("v_permlane32_swap_b32 %0, %1" : "+v"(w5), "+v"(w7));        \
    u32x4 a0_ = {w0, w1, w2, w3};                                    \
    u32x4 a1_ = {w4, w5, w6, w7};                                    \
    kb0 = __builtin_bit_cast(bf16x8, a0_);                           \
    kb1 = __builtin_bit_cast(bf16x8, a1_);                           \
  }

// ---------------------------------------------------------------------------
// Kernel A v5: single-writer blocks, no atomics, no cvt pass.
//   kv_b[bh][d][m] = sum_l V[l][d]*kp[l][m] (bf16), ksum_ws[bh][m] = sum_l kp
//   kp = relu(K·projT)+eps
// 320 blocks x 512 thr (8 waves). Block = (mc, bh) via XCD-clustered remap
// (all 5 mc of one bh land on the same XCD -> K/V re-reads are L2 hits).
// Wave (s,h): l-slice s in [0,4), m-half h in [0,2). Per 128-l tile:
// T14 staging (next-tile loads issued before compute), 4+4 MFMA32 per wave.
// Epilogue: 4-phase LDS slice reduction, coalesced bf16/f32 stores (pad->0).
// ---------------------------------------------------------------------------
__global__ __launch_bounds__(512, 2) void perf_kv_fused(
    const float* __restrict__ kg, const float* __restrict__ vg,
    const float* __restrict__ proj, bf16* __restrict__ kv_b,
    float* __restrict__ ksum_ws)
{
  __shared__ __align__(16) bf16 k_lds[TL * STR];     // [128 l][64 d] 18432 B
  __shared__ __align__(16) bf16 vt_lds[64 * VTS];    // [64 d][128 l] 17408 B
  __shared__ float red_lds[2 * 64 * 33];             // [h][d][m32]   16896 B
  __shared__ float ksr_lds[8 * 32];                  //                1024 B

  const int t    = threadIdx.x;
  const int wid  = t >> 6;
  const int lane = t & 63;
  const int ln31 = lane & 31;
  const int hi   = lane >> 5;
  const int s    = wid & 3;   // l-slice within tile
  const int h    = wid >> 2;  // m-half

  // XCD-clustered block remap: id = k5*8 + r8; all 5 mc of a bh share r8 (XCD)
  const int id = blockIdx.x;
  const int k5 = id >> 3, r8 = id & 7;
  const int mc = k5 % 5;
  const int bh = r8 + 8 * (k5 / 5);
  const int m0 = mc * 64;

  // proj B-fragments (register-resident): col m = m0+h*32+ln31, k(d)=ks*16+hi*8
  bf16x8 pb[4];
  {
    const int m = m0 + h * 32 + ln31;
#pragma unroll
    for (int ks = 0; ks < 4; ++ks) {
      bf16x8 w = {};
      if (m < MN) {
        const float* p = proj + m * 64 + ks * 16 + hi * 8;
        f4 a = *(const f4*)p;
        f4 b = *(const f4*)(p + 4);
        w = (bf16x8){(bf16)a.x, (bf16)a.y, (bf16)a.z, (bf16)a.w,
                     (bf16)b.x, (bf16)b.y, (bf16)b.z, (bf16)b.w};
      }
      pb[ks] = w;
    }
  }

  f32x16 acc0 = (f32x16){};  // kvT rows d = (r&3)+8*(r>>2)+4*hi,      col m
  f32x16 acc1 = (f32x16){};  // kvT rows d = 32 + same,                col m
  float ksum_acc = 0.f;

  const f4* kg4 = (const f4*)kg + ((size_t)bh * LN) * 16;
  const f4* vg4 = (const f4*)vg + ((size_t)bh * LN) * 16;

  f4 kreg[4], vra[2], vrb[2];

  auto LOAD = [&](int tile) {
    const int l0 = tile * TL;
#pragma unroll
    for (int i = 0; i < 4; ++i) {
      int idx = t + i * 512;
      kreg[i] = kg4[(l0 + (idx >> 4)) * 16 + (idx & 15)];
    }
#pragma unroll
    for (int i = 0; i < 2; ++i) {
      int u = t + i * 512;
      int lb2 = u >> 4, d4 = u & 15;
      vra[i] = vg4[(l0 + lb2 * 2) * 16 + d4];
      vrb[i] = vg4[(l0 + lb2 * 2 + 1) * 16 + d4];
    }
  };
  auto WRITE = [&]() {
#pragma unroll
    for (int i = 0; i < 4; ++i) {
      int idx = t + i * 512;
      int row = idx >> 4, d4 = idx & 15;
      f4 val = kreg[i];
      bf16x4 w = {(bf16)val.x, (bf16)val.y, (bf16)val.z, (bf16)val.w};
      *(bf16x4*)&k_lds[row * STR + d4 * 4] = w;
    }
#pragma unroll
    for (int i = 0; i < 2; ++i) {
      int u = t + i * 512;
      int lb2 = u >> 4, d4 = u & 15;
      f4 a = vra[i], b = vrb[i];
      bf16x2 w0 = {(bf16)a.x, (bf16)b.x};
      bf16x2 w1 = {(bf16)a.y, (bf16)b.y};
      bf16x2 w2 = {(bf16)a.z, (bf16)b.z};
      bf16x2 w3 = {(bf16)a.w, (bf16)b.w};
      *(bf16x2*)&vt_lds[(d4 * 4 + 0) * VTS + lb2 * 2] = w0;
      *(bf16x2*)&vt_lds[(d4 * 4 + 1) * VTS + lb2 * 2] = w1;
      *(bf16x2*)&vt_lds[(d4 * 4 + 2) * VTS + lb2 * 2] = w2;
      *(bf16x2*)&vt_lds[(d4 * 4 + 3) * VTS + lb2 * 2] = w3;
    }
  };

  LOAD(0);
  for (int tile = 0; tile < NT; ++tile) {
    __syncthreads();                    // prev tile consumed
    WRITE();                            // (waits vmcnt for this tile's loads)
    if (tile < NT - 1) LOAD(tile + 1);  // in flight across compute
    __syncthreads();                    // tile ready

    // K A-frags: row l = s*32+ln31 (local), k(d) = ks*16+hi*8
    bf16x8 ka[4];
#pragma unroll
    for (int ks = 0; ks < 4; ++ks)
      ka[ks] = *(const bf16x8*)&k_lds[(s * 32 + ln31) * STR + ks * 16 + hi * 8];
    // V^T A-frags: row d = dt*32+ln31, k(l) = s*32 + kk*16+hi*8
    bf16x8 va00 = *(const bf16x8*)&vt_lds[ln31 * VTS + s * 32 + hi * 8];
    bf16x8 va01 = *(const bf16x8*)&vt_lds[ln31 * VTS + s * 32 + 16 + hi * 8];
    bf16x8 va10 = *(const bf16x8*)&vt_lds[(32 + ln31) * VTS + s * 32 + hi * 8];
    bf16x8 va11 = *(const bf16x8*)&vt_lds[(32 + ln31) * VTS + s * 32 + 16 + hi * 8];

    // feature: C1[l][m] = K·projT (lane = m col, regs = l rows)
    f32x16 f = (f32x16){};
#pragma unroll
    for (int ks = 0; ks < 4; ++ks) f = MFMA32(ka[ks], pb[ks], f);
#pragma unroll
    for (int i = 0; i < 16; ++i) f[i] = fmaxf(f[i], 0.f) + EPSF;
    ksum_acc += f[0] + f[1] + f[2] + f[3] + f[4] + f[5] + f[6] + f[7]
              + f[8] + f[9] + f[10] + f[11] + f[12] + f[13] + f[14] + f[15];

    bf16x8 kb0, kb1;
    T12_TRANSFORM(f, kb0, kb1)
    acc0 = MFMA32(va00, kb0, acc0);
    acc0 = MFMA32(va01, kb1, acc0);
    acc1 = MFMA32(va10, kb0, acc1);
    acc1 = MFMA32(va11, kb1, acc1);
  }

  // ---- epilogue: slice reduction in LDS, then single-writer stores ----
  {
    float rr = ksum_acc + __shfl_xor(ksum_acc, 32);  // both hi halves
    if (hi == 0) ksr_lds[(h * 4 + s) * 32 + ln31] = rr;
  }
  if (s == 0) {
#pragma unroll
    for (int r = 0; r < 16; ++r) {
      int d0 = (r & 3) + 8 * (r >> 2) + 4 * hi;
      red_lds[(h * 64 + d0) * 33 + ln31] = acc0[r];
      red_lds[(h * 64 + 32 + d0) * 33 + ln31] = acc1[r];
    }
  }
  __syncthreads();
#pragma unroll
  for (int ph = 1; ph < 4; ++ph) {
    if (s == ph) {
#pragma unroll
      for (int r = 0; r < 16; ++r) {
        int d0 = (r & 3) + 8 * (r >> 2) + 4 * hi;
        red_lds[(h * 64 + d0) * 33 + ln31] += acc0[r];
        red_lds[(h * 64 + 32 + d0) * 33 + ln31] += acc1[r];
      }
    }
    __syncthreads();
  }

  // kv store: thread -> (d = t>>3, 8 m at m8*8); pad m stored as exact 0
  {
    const int dq = t >> 3, m8 = t & 7;
    const int hh = m8 >> 2, cb = (m8 & 3) * 8;
    bf16x8 w;
#pragma unroll
    for (int j = 0; j < 8; ++j) {
      float v = red_lds[(hh * 64 + dq) * 33 + cb + j];
      w[j] = (m0 + m8 * 8 + j < MN) ? (bf16)v : (bf16)0.f;
    }
    *(bf16x8*)&kv_b[((size_t)bh * 64 + dq) * MP + m0 + m8 * 8] = w;
  }
  if (t < 64) {
    const int hh = t >> 5, col = t & 31;
    float v = ksr_lds[(hh * 4 + 0) * 32 + col] + ksr_lds[(hh * 4 + 1) * 32 + col]
            + ksr_lds[(hh * 4 + 2) * 32 + col] + ksr_lds[(hh * 4 + 3) * 32 + col];
    ksum_ws[bh * MP + m0 + t] = (m0 + t < MN) ? v : 0.f;
  }
}

// ---------------------------------------------------------------------------
// Kernel B (r4-verified structure; now converts proj f32->bf16 itself)
// ---------------------------------------------------------------------------
__global__ __launch_bounds__(512, 2) void perf_out_mfma32(
    const float* __restrict__ qg, const float* __restrict__ proj,
    const bf16* __restrict__ kvb, const float* __restrict__ ksum_ws,
    float* __restrict__ outg)
{
  __shared__ __align__(16) bf16 pj_lds[MP * STR];   // [m][d]
  __shared__ __align__(16) bf16 kv_lds[DN * KVS];   // [d][m]
  __shared__ __align__(16) float ksum_lds[MP];
  __shared__ float dp_lds[8 * 64];

  const int t    = threadIdx.x;
  const int wid  = t >> 6;
  const int lane = t & 63;
  const int ln31 = lane & 31;
  const int hi   = lane >> 5;
  const int bh   = blockIdx.y;
  const int lbase = blockIdx.x * 1024;

  // stage proj f32 -> bf16 (zero-padded m >= 266); constant trip (10)
  {
    const f4* projv = (const f4*)proj;
#pragma unroll
    for (int i = 0; i < 10; ++i) {
      int idx = t + i * 512;
      int r = idx >> 4, c4 = idx & 15;
      f4 v = {0.f, 0.f, 0.f, 0.f};
      if (r < MN) v = projv[r * 16 + c4];
      bf16x4 w = {(bf16)v.x, (bf16)v.y, (bf16)v.z, (bf16)v.w};
      *(bf16x4*)&pj_lds[r * STR + c4 * 4] = w;
    }
  }
  for (int idx = t; idx < DN * 40; idx += 512) {
    int r = idx / 40, cc = idx % 40;
    *(bf16x8*)&kv_lds[r * KVS + cc * 8] =
        *(const bf16x8*)&kvb[((size_t)bh * DN + r) * MP + cc * 8];
  }
  if (t < MP) ksum_lds[t] = ksum_ws[bh * MP + t];
  __syncthreads();  // the only block barrier

  for (int rnd = 0; rnd < 2; ++rnd) {
    const int lw = lbase + rnd * 512 + wid * 64;

    bf16x8 qb[2][4];
#pragma unroll
    for (int lt = 0; lt < 2; ++lt)
#pragma unroll
      for (int ks = 0; ks < 4; ++ks) {
        const float* qp_ = qg + ((size_t)bh * LN + lw + lt * 32 + ln31) * 64 + ks * 16 + hi * 8;
        f4 a = *(const f4*)qp_;
        f4 b = *(const f4*)(qp_ + 4);
        qb[lt][ks] = (bf16x8){(bf16)a.x, (bf16)a.y, (bf16)a.z, (bf16)a.w,
                              (bf16)b.x, (bf16)b.y, (bf16)b.z, (bf16)b.w};
      }

    f32x16 oc[2][2];
    oc[0][0] = (f32x16){}; oc[0][1] = (f32x16){};
    oc[1][0] = (f32x16){}; oc[1][1] = (f32x16){};
    float dp[2] = {0.f, 0.f};

    for (int mc = 0; mc < 5; ++mc) {
      f32x16 c2[2][2];
      c2[0][0] = (f32x16){}; c2[0][1] = (f32x16){};
      c2[1][0] = (f32x16){}; c2[1][1] = (f32x16){};
#pragma unroll
      for (int ks = 0; ks < 4; ++ks) {
        bf16x8 pa0 = *(const bf16x8*)&pj_lds[(mc * 64 + ln31) * STR + ks * 16 + hi * 8];
        bf16x8 pa1 = *(const bf16x8*)&pj_lds[(mc * 64 + 32 + ln31) * STR + ks * 16 + hi * 8];
        c2[0][0] = MFMA32(pa0, qb[0][ks], c2[0][0]);
        c2[1][0] = MFMA32(pa0, qb[1][ks], c2[1][0]);
        c2[0][1] = MFMA32(pa1, qb[0][ks], c2[0][1]);
        c2[1][1] = MFMA32(pa1, qb[1][ks], c2[1][1]);
      }
#pragma unroll
      for (int mt = 0; mt < 2; ++mt) {
        const int mb = mc * 64 + mt * 32 + 4 * hi;
        f32x4 kq0 = *(const f32x4*)&ksum_lds[mb + 0];
        f32x4 kq1 = *(const f32x4*)&ksum_lds[mb + 8];
        f32x4 kq2 = *(const f32x4*)&ksum_lds[mb + 16];
        f32x4 kq3 = *(const f32x4*)&ksum_lds[mb + 24];
        bf16x8 A[2][2];
#pragma unroll
        for (int lt = 0; lt < 2; ++lt) {
          f32x16 f = c2[lt][mt];
#pragma unroll
          for (int i = 0; i < 16; ++i) f[i] = fmaxf(f[i], 0.f) + EPSF;
          dp[lt] += f[0] * kq0[0] + f[1] * kq0[1] + f[2] * kq0[2] + f[3] * kq0[3]
                  + f[4] * kq1[0] + f[5] * kq1[1] + f[6] * kq1[2] + f[7] * kq1[3]
                  + f[8] * kq2[0] + f[9] * kq2[1] + f[10] * kq2[2] + f[11] * kq2[3]
                  + f[12] * kq3[0] + f[13] * kq3[1] + f[14] * kq3[2] + f[15] * kq3[3];
          bf16x8 kb0, kb1;
          T12_TRANSFORM(f, kb0, kb1)
          A[lt][0] = kb0;
          A[lt][1] = kb1;
        }
#pragma unroll
        for (int kk = 0; kk < 2; ++kk) {
          const int mo = mc * 64 + (mt * 2 + kk) * 16 + hi * 8;
          bf16x8 kb0 = *(const bf16x8*)&kv_lds[ln31 * KVS + mo];
          bf16x8 kb1 = *(const bf16x8*)&kv_lds[(32 + ln31) * KVS + mo];
          oc[0][0] = MFMA32(A[0][kk], kb0, oc[0][0]);
          oc[1][0] = MFMA32(A[1][kk], kb0, oc[1][0]);
          oc[0][1] = MFMA32(A[0][kk], kb1, oc[0][1]);
          oc[1][1] = MFMA32(A[1][kk], kb1, oc[1][1]);
        }
      }
    }

#pragma unroll
    for (int lt = 0; lt < 2; ++lt) {
      float r = dp[lt];
      r += __shfl_xor(r, 32);
      dp_lds[wid * 64 + lt * 32 + ln31] = r;
    }
#pragma unroll
    for (int lt = 0; lt < 2; ++lt) {
#pragma unroll
      for (int rg = 0; rg < 4; ++rg) {
        f32x4 dv = *(const f32x4*)&dp_lds[wid * 64 + lt * 32 + 8 * rg + 4 * hi];
        f32x4 di = {1.f / dv[0], 1.f / dv[1], 1.f / dv[2], 1.f / dv[3]};
#pragma unroll
        for (int dt = 0; dt < 2; ++dt) {
#pragma unroll
          for (int j = 0; j < 4; ++j) {
            int l = lw + lt * 32 + 8 * rg + 4 * hi + j;
            outg[((size_t)bh * LN + l) * DN + dt * 32 + ln31] = oc[lt][dt][4 * rg + j] * di[j];
          }
        }
      }
    }
  }
}

// ---------------------------------------------------------------------------
extern "C" void kernel_launch(void* const* d_in, const int* in_sizes, int n_in,
                              void* d_out, int out_size, void* d_ws, size_t ws_size,
                              hipStream_t stream)
{
  const float* q    = (const float*)d_in[0];
  const float* k    = (const float*)d_in[1];
  const float* v    = (const float*)d_in[2];
  const float* proj = (const float*)d_in[3];
  float* out = (float*)d_out;

  float* ksum_ws = (float*)d_ws;                        // [64][320] f32
  bf16*  kv_b    = (bf16*)(ksum_ws + (size_t)BHN * MP); // [64][64][320] bf16
  // Both arrays fully written by perf_kv_fused (single writer per element,
  // pad entries stored as 0) -> no memset needed, no atomics anywhere.

  perf_kv_fused<<<320, 512, 0, stream>>>(k, v, proj, kv_b, ksum_ws);
  perf_out_mfma32<<<dim3(LN / 1024, BHN), 512, 0, stream>>>(q, proj, kv_b, ksum_ws, out);
}